// Round 1
// baseline (22377.692 us; speedup 1.0000x reference)
//
#include <hip/hip_runtime.h>

#define N_USERS 100000
#define N_ITEMS 50000
#define NTOT    150000
#define DD      64
#define NNZV    6400000
#define ALPHA_  0.3f

static constexpr size_t SZ = (size_t)NTOT * DD; // 9,600,000 floats per channel buffer

// ---------------- dense GEMM + bias: C[M,64] = A[M,K] @ W[K,64] + b ----------------
__global__ __launch_bounds__(256) void gemm_bias(
    const float* __restrict__ A, const float* __restrict__ W,
    const float* __restrict__ bias, float* __restrict__ C, int M, int K)
{
    __shared__ float As[16][64];  // [k][m]
    __shared__ float Bs[16][64];  // [k][n]
    const int t  = threadIdx.x;
    const int tx = t & 15, ty = t >> 4;
    const int lr = t >> 2;          // A-tile row for loads
    const int lk = (t & 3) << 2;    // A-tile k offset for loads
    const int brow = t >> 4;        // B-tile k row for loads
    const int bc   = (t & 15) << 2; // B-tile col for loads
    const int block_row = blockIdx.x << 6;

    float acc[4][4] = {{0.f,0.f,0.f,0.f},{0.f,0.f,0.f,0.f},{0.f,0.f,0.f,0.f},{0.f,0.f,0.f,0.f}};

    const int grow = block_row + lr;
    const bool arow_ok = (grow < M);
    const float* Aptr = A + (size_t)grow * K;

    for (int k0 = 0; k0 < K; k0 += 16) {
        float4 av = make_float4(0.f, 0.f, 0.f, 0.f);
        if (arow_ok) av = *(const float4*)(Aptr + k0 + lk);
        As[lk+0][lr] = av.x; As[lk+1][lr] = av.y; As[lk+2][lr] = av.z; As[lk+3][lr] = av.w;
        *(float4*)&Bs[brow][bc] = *(const float4*)(W + (size_t)(k0 + brow) * DD + bc);
        __syncthreads();
        #pragma unroll
        for (int k = 0; k < 16; ++k) {
            float4 a = *(const float4*)&As[k][ty << 2];
            float4 b = *(const float4*)&Bs[k][tx << 2];
            acc[0][0] += a.x*b.x; acc[0][1] += a.x*b.y; acc[0][2] += a.x*b.z; acc[0][3] += a.x*b.w;
            acc[1][0] += a.y*b.x; acc[1][1] += a.y*b.y; acc[1][2] += a.y*b.z; acc[1][3] += a.y*b.w;
            acc[2][0] += a.z*b.x; acc[2][1] += a.z*b.y; acc[2][2] += a.z*b.z; acc[2][3] += a.z*b.w;
            acc[3][0] += a.w*b.x; acc[3][1] += a.w*b.y; acc[3][2] += a.w*b.z; acc[3][3] += a.w*b.w;
        }
        __syncthreads();
    }
    const float4 bv = *(const float4*)(bias + (tx << 2));
    #pragma unroll
    for (int i = 0; i < 4; ++i) {
        int row = block_row + (ty << 2) + i;
        if (row < M) {
            float4 o = make_float4(acc[i][0] + bv.x, acc[i][1] + bv.y,
                                   acc[i][2] + bv.z, acc[i][3] + bv.w);
            *(float4*)(C + (size_t)row * DD + (tx << 2)) = o;
        }
    }
}

// ---------------- row-wise L2 normalize (in place), 1 wave per row ----------------
__global__ __launch_bounds__(256) void l2norm_rows(float* __restrict__ x, int nrows)
{
    int row  = blockIdx.x * 4 + (threadIdx.x >> 6);
    int lane = threadIdx.x & 63;
    if (row >= nrows) return;
    float v = x[(size_t)row * DD + lane];
    float s = v * v;
    #pragma unroll
    for (int off = 32; off > 0; off >>= 1) s += __shfl_xor(s, off);
    float n = sqrtf(s);
    x[(size_t)row * DD + lane] = v / fmaxf(n, 1e-12f);
}

// ---------------- simple float4 copy ----------------
__global__ __launch_bounds__(256) void copy4(const float4* __restrict__ src,
                                             float4* __restrict__ dst, int n4)
{
    int i = blockIdx.x * 256 + threadIdx.x;
    if (i < n4) dst[i] = src[i];
}

// ---------------- dst = alpha * src ----------------
__global__ __launch_bounds__(256) void scale4(const float4* __restrict__ src,
                                              float4* __restrict__ dst, int n4)
{
    int i = blockIdx.x * 256 + threadIdx.x;
    if (i < n4) {
        float4 v = src[i];
        dst[i] = make_float4(ALPHA_*v.x, ALPHA_*v.y, ALPHA_*v.z, ALPHA_*v.w);
    }
}

// ---------------- COO spmm accumulate: out[row] += val * x[col]; 16 lanes/nnz ----------------
__global__ __launch_bounds__(256) void spmm_atomic(
    const float* __restrict__ vals, const int* __restrict__ rows,
    const int* __restrict__ cols, const float* __restrict__ x,
    float* __restrict__ out, int nnz)
{
    long long tid = (long long)blockIdx.x * 256 + threadIdx.x;
    int g = (int)(tid >> 4);
    if (g >= nnz) return;
    int lane = (int)(tid & 15);
    float v = vals[g];
    int r = rows[g], c = cols[g];
    float4 xv = *((const float4*)(x + (size_t)c * DD) + lane);
    float* o = out + (size_t)r * DD + (lane << 2);
    atomicAdd(o + 0, v * xv.x);
    atomicAdd(o + 1, v * xv.y);
    atomicAdd(o + 2, v * xv.z);
    atomicAdd(o + 3, v * xv.w);
}

// ---------------- final layout: out[row, 0:64]=egoI[row], out[row, 64:128]=egoT[row] ----------------
__global__ __launch_bounds__(256) void finalize_k(
    const float4* __restrict__ egoI, const float4* __restrict__ egoT,
    float4* __restrict__ out)
{
    int tid = blockIdx.x * 256 + threadIdx.x; // 150000*32 float4 slots
    int row = tid >> 5, q = tid & 31;
    if (row >= NTOT) return;
    float4 v = (q < 16) ? egoI[(size_t)row * 16 + q] : egoT[(size_t)row * 16 + (q - 16)];
    out[tid] = v;
}

extern "C" void kernel_launch(void* const* d_in, const int* in_sizes, int n_in,
                              void* d_out, int out_size, void* d_ws, size_t ws_size,
                              hipStream_t stream)
{
    const float* image_feats = (const float*)d_in[0];
    const float* text_feats  = (const float*)d_in[1];
    const float* image_pref  = (const float*)d_in[2];
    const float* text_pref   = (const float*)d_in[3];
    const float* W_img       = (const float*)d_in[4];
    const float* b_img       = (const float*)d_in[5];
    const float* W_txt       = (const float*)d_in[6];
    const float* b_txt       = (const float*)d_in[7];
    const float* adj_vals    = (const float*)d_in[8];
    const int*   adj_rows    = (const int*)d_in[9];
    const int*   adj_cols    = (const int*)d_in[10];

    float* out = (float*)d_out;
    float* wsf = (float*)d_ws;

    // ping-pong buffers: A-set in ws, B-set aliased onto d_out (rewritten at the end)
    float* Ai = wsf;            // ego_i  (A)
    float* At = wsf + SZ;       // ego_t  (A)
    float* Bi = out;            // ego_i  (B, scratch in d_out)
    float* Bt = out + SZ;       // ego_t  (B, scratch in d_out)

    const int n4_pref = N_USERS * DD / 4;   // 1.6M
    const int n4_ego  = (int)(SZ / 4);      // 2.4M

    // 1) ego init: user prefs
    copy4<<<n4_pref / 256, 256, 0, stream>>>((const float4*)image_pref, (float4*)Ai, n4_pref);
    copy4<<<n4_pref / 256, 256, 0, stream>>>((const float4*)text_pref,  (float4*)At, n4_pref);

    // 2) item embeddings (GEMM + bias), then L2 norm, into rows [N_USERS, NTOT)
    gemm_bias<<<(N_ITEMS + 63) / 64, 256, 0, stream>>>(image_feats, W_img, b_img,
                                                       Ai + (size_t)N_USERS * DD, N_ITEMS, 4096);
    gemm_bias<<<(N_ITEMS + 63) / 64, 256, 0, stream>>>(text_feats,  W_txt, b_txt,
                                                       At + (size_t)N_USERS * DD, N_ITEMS, 384);
    l2norm_rows<<<(N_ITEMS + 3) / 4, 256, 0, stream>>>(Ai + (size_t)N_USERS * DD, N_ITEMS);
    l2norm_rows<<<(N_ITEMS + 3) / 4, 256, 0, stream>>>(At + (size_t)N_USERS * DD, N_ITEMS);

    const int spmm_blocks = (int)(((long long)NNZV * 16 + 255) / 256);

    // 3) layer 1: A -> B   (B = 0.3*A, then B += adj @ A)
    scale4<<<(n4_ego + 255) / 256, 256, 0, stream>>>((const float4*)Ai, (float4*)Bi, n4_ego);
    spmm_atomic<<<spmm_blocks, 256, 0, stream>>>(adj_vals, adj_rows, adj_cols, Ai, Bi, NNZV);
    scale4<<<(n4_ego + 255) / 256, 256, 0, stream>>>((const float4*)At, (float4*)Bt, n4_ego);
    spmm_atomic<<<spmm_blocks, 256, 0, stream>>>(adj_vals, adj_rows, adj_cols, At, Bt, NNZV);

    // 4) layer 2: B -> A
    scale4<<<(n4_ego + 255) / 256, 256, 0, stream>>>((const float4*)Bi, (float4*)Ai, n4_ego);
    spmm_atomic<<<spmm_blocks, 256, 0, stream>>>(adj_vals, adj_rows, adj_cols, Bi, Ai, NNZV);
    scale4<<<(n4_ego + 255) / 256, 256, 0, stream>>>((const float4*)Bt, (float4*)At, n4_ego);
    spmm_atomic<<<spmm_blocks, 256, 0, stream>>>(adj_vals, adj_rows, adj_cols, Bt, At, NNZV);

    // 5) final interleave from A buffers into d_out
    finalize_k<<<(NTOT * 32) / 256, 256, 0, stream>>>((const float4*)Ai, (const float4*)At,
                                                      (float4*)out);
}

// Round 2
// 2488.705 us; speedup vs baseline: 8.9917x; 8.9917x over previous
//
#include <hip/hip_runtime.h>

#define N_USERS 100000
#define N_ITEMS 50000
#define NTOT    150000
#define DD      64
#define NNZV    6400000
#define ALPHA_  0.3f

static constexpr size_t SZ  = (size_t)NTOT * DD;   // 9.6M floats (one 64-wide channel)
static constexpr size_t SZ2 = (size_t)NTOT * 128;  // 19.2M floats (combined buffer)

// ================= dense GEMM + bias: C[M,64] = A[M,K] @ W[K,64] + b (ldc param) ==========
__global__ __launch_bounds__(256) void gemm_bias(
    const float* __restrict__ A, const float* __restrict__ W,
    const float* __restrict__ bias, float* __restrict__ C, int M, int K, int ldc)
{
    __shared__ float As[16][64];  // [k][m]
    __shared__ float Bs[16][64];  // [k][n]
    const int t  = threadIdx.x;
    const int tx = t & 15, ty = t >> 4;
    const int lr = t >> 2;          // A-tile row for loads
    const int lk = (t & 3) << 2;    // A-tile k offset for loads
    const int brow = t >> 4;        // B-tile k row for loads
    const int bc   = (t & 15) << 2; // B-tile col for loads
    const int block_row = blockIdx.x << 6;

    float acc[4][4] = {{0.f,0.f,0.f,0.f},{0.f,0.f,0.f,0.f},{0.f,0.f,0.f,0.f},{0.f,0.f,0.f,0.f}};

    const int grow = block_row + lr;
    const bool arow_ok = (grow < M);
    const float* Aptr = A + (size_t)grow * K;

    for (int k0 = 0; k0 < K; k0 += 16) {
        float4 av = make_float4(0.f, 0.f, 0.f, 0.f);
        if (arow_ok) av = *(const float4*)(Aptr + k0 + lk);
        As[lk+0][lr] = av.x; As[lk+1][lr] = av.y; As[lk+2][lr] = av.z; As[lk+3][lr] = av.w;
        *(float4*)&Bs[brow][bc] = *(const float4*)(W + (size_t)(k0 + brow) * DD + bc);
        __syncthreads();
        #pragma unroll
        for (int k = 0; k < 16; ++k) {
            float4 a = *(const float4*)&As[k][ty << 2];
            float4 b = *(const float4*)&Bs[k][tx << 2];
            acc[0][0] += a.x*b.x; acc[0][1] += a.x*b.y; acc[0][2] += a.x*b.z; acc[0][3] += a.x*b.w;
            acc[1][0] += a.y*b.x; acc[1][1] += a.y*b.y; acc[1][2] += a.y*b.z; acc[1][3] += a.y*b.w;
            acc[2][0] += a.z*b.x; acc[2][1] += a.z*b.y; acc[2][2] += a.z*b.z; acc[2][3] += a.z*b.w;
            acc[3][0] += a.w*b.x; acc[3][1] += a.w*b.y; acc[3][2] += a.w*b.z; acc[3][3] += a.w*b.w;
        }
        __syncthreads();
    }
    const float4 bv = *(const float4*)(bias + (tx << 2));
    #pragma unroll
    for (int i = 0; i < 4; ++i) {
        int row = block_row + (ty << 2) + i;
        if (row < M) {
            float4 o = make_float4(acc[i][0] + bv.x, acc[i][1] + bv.y,
                                   acc[i][2] + bv.z, acc[i][3] + bv.w);
            *(float4*)(C + (size_t)row * ldc + (tx << 2)) = o;
        }
    }
}

// ================= row-wise L2 normalize (in place), 1 wave per row, ld param =============
__global__ __launch_bounds__(256) void l2norm_rows(float* __restrict__ x, int nrows, int ld)
{
    int row  = blockIdx.x * 4 + (threadIdx.x >> 6);
    int lane = threadIdx.x & 63;
    if (row >= nrows) return;
    float v = x[(size_t)row * ld + lane];
    float s = v * v;
    #pragma unroll
    for (int off = 32; off > 0; off >>= 1) s += __shfl_xor(s, off);
    float n = sqrtf(s);
    x[(size_t)row * ld + lane] = v / fmaxf(n, 1e-12f);
}

// ================= float4 copy ==============================================
__global__ __launch_bounds__(256) void copy4(const float4* __restrict__ src,
                                             float4* __restrict__ dst, int n4)
{
    int i = blockIdx.x * 256 + threadIdx.x;
    if (i < n4) dst[i] = src[i];
}

// ================= interleave user prefs into X[row][0:64|64:128] ===========
__global__ __launch_bounds__(256) void build_user(const float4* __restrict__ ip,
                                                  const float4* __restrict__ tp,
                                                  float4* __restrict__ X)
{
    int i = blockIdx.x * 256 + threadIdx.x;   // N_USERS*16 float4 per channel
    if (i >= N_USERS * 16) return;
    int row = i >> 4, q = i & 15;
    X[(size_t)row * 32 + q]      = ip[i];
    X[(size_t)row * 32 + 16 + q] = tp[i];
}

// ================= counting sort by row =====================================
__global__ __launch_bounds__(256) void hist_k(const int* __restrict__ rows, int* __restrict__ hist)
{
    int i = blockIdx.x * 256 + threadIdx.x;
    if (i < NNZV) atomicAdd(&hist[rows[i]], 1);
}

// per-block exclusive scan (1024 elems/block), emits block totals
__global__ __launch_bounds__(256) void scan_block(const int* __restrict__ in, int* __restrict__ out,
                                                  int* __restrict__ partials, int n)
{
    __shared__ int sh[256];
    int t = threadIdx.x;
    int base = blockIdx.x * 1024 + t * 4;
    int v0 = 0, v1 = 0, v2 = 0, v3 = 0;
    if (base + 3 < n) { int4 x = *(const int4*)(in + base); v0 = x.x; v1 = x.y; v2 = x.z; v3 = x.w; }
    else {
        if (base     < n) v0 = in[base];
        if (base + 1 < n) v1 = in[base + 1];
        if (base + 2 < n) v2 = in[base + 2];
        if (base + 3 < n) v3 = in[base + 3];
    }
    int tsum = v0 + v1 + v2 + v3;
    sh[t] = tsum;
    __syncthreads();
    for (int off = 1; off < 256; off <<= 1) {
        int x = 0;
        if (t >= off) x = sh[t - off];
        __syncthreads();
        sh[t] += x;
        __syncthreads();
    }
    int texcl = sh[t] - tsum;
    if (t == 255) partials[blockIdx.x] = sh[255];
    int e0 = texcl, e1 = e0 + v0, e2 = e1 + v1, e3 = e2 + v2;
    if (base + 3 < n) { *(int4*)(out + base) = make_int4(e0, e1, e2, e3); }
    else {
        if (base     < n) out[base]     = e0;
        if (base + 1 < n) out[base + 1] = e1;
        if (base + 2 < n) out[base + 2] = e2;
        if (base + 3 < n) out[base + 3] = e3;
    }
}

__global__ __launch_bounds__(256) void scan_partials(int* __restrict__ p, int np)
{
    __shared__ int sh[256];
    int t = threadIdx.x;
    int v = (t < np) ? p[t] : 0;
    sh[t] = v;
    __syncthreads();
    for (int off = 1; off < 256; off <<= 1) {
        int x = 0;
        if (t >= off) x = sh[t - off];
        __syncthreads();
        sh[t] += x;
        __syncthreads();
    }
    if (t < np) p[t] = sh[t] - v;
}

__global__ __launch_bounds__(256) void add_offsets(int* __restrict__ out,
                                                   const int* __restrict__ partials, int n)
{
    int i = blockIdx.x * 256 + threadIdx.x;
    if (i < n) out[i] += partials[i >> 10];
}

__global__ void set_tail(int* __restrict__ rstart)
{
    if (threadIdx.x == 0 && blockIdx.x == 0) rstart[NTOT] = NNZV;
}

// scatter (val,col) pairs into row-sorted order
__global__ __launch_bounds__(256) void scatter_k(
    const float* __restrict__ vals, const int* __restrict__ rows, const int* __restrict__ cols,
    int* __restrict__ cursor, int2* __restrict__ spair)
{
    int i = blockIdx.x * 256 + threadIdx.x;
    if (i >= NNZV) return;
    int r = rows[i];
    int p = atomicAdd(&cursor[r], 1);
    spair[p] = make_int2(__float_as_int(vals[i]), cols[i]);
}

// ================= per-row SpMM, combined 128-wide channels, no atomics =====
// out[row][0:128] = sum_j val_j * Xin[col_j][0:128] + alpha * Xin[row][0:128]
__global__ __launch_bounds__(256) void spmm_rows(
    const int2* __restrict__ spair, const int* __restrict__ rstart,
    const float* __restrict__ Xin, float* __restrict__ Xout)
{
    int row  = (blockIdx.x << 2) + (threadIdx.x >> 6);
    int lane = threadIdx.x & 63;
    if (row >= NTOT) return;
    int beg = rstart[row];
    int end = rstart[row + 1];
    float a0 = 0.f, a1 = 0.f;
    for (int j0 = beg; j0 < end; j0 += 64) {
        int nj = end - j0; if (nj > 64) nj = 64;
        float vv = 0.f; int cc = 0;
        if (lane < nj) {
            int2 pc = spair[j0 + lane];
            vv = __int_as_float(pc.x);
            cc = pc.y;
        }
        for (int jj = 0; jj < nj; ++jj) {
            float v = __shfl(vv, jj);
            int   c = __shfl(cc, jj);
            const float* xp = Xin + (size_t)c * 128;
            a0 += v * xp[lane];
            a1 += v * xp[64 + lane];
        }
    }
    const float* xr = Xin + (size_t)row * 128;
    size_t o = (size_t)row * 128 + lane;
    Xout[o]      = a0 + ALPHA_ * xr[lane];
    Xout[o + 64] = a1 + ALPHA_ * xr[64 + lane];
}

// ================= fallback (round-1) kernels ===============================
__global__ __launch_bounds__(256) void scale4(const float4* __restrict__ src,
                                              float4* __restrict__ dst, int n4)
{
    int i = blockIdx.x * 256 + threadIdx.x;
    if (i < n4) {
        float4 v = src[i];
        dst[i] = make_float4(ALPHA_*v.x, ALPHA_*v.y, ALPHA_*v.z, ALPHA_*v.w);
    }
}

__global__ __launch_bounds__(256) void spmm_atomic(
    const float* __restrict__ vals, const int* __restrict__ rows,
    const int* __restrict__ cols, const float* __restrict__ x,
    float* __restrict__ out, int nnz)
{
    long long tid = (long long)blockIdx.x * 256 + threadIdx.x;
    int g = (int)(tid >> 4);
    if (g >= nnz) return;
    int lane = (int)(tid & 15);
    float v = vals[g];
    int r = rows[g], c = cols[g];
    float4 xv = *((const float4*)(x + (size_t)c * DD) + lane);
    float* o = out + (size_t)r * DD + (lane << 2);
    atomicAdd(o + 0, v * xv.x);
    atomicAdd(o + 1, v * xv.y);
    atomicAdd(o + 2, v * xv.z);
    atomicAdd(o + 3, v * xv.w);
}

__global__ __launch_bounds__(256) void finalize_k(
    const float4* __restrict__ egoI, const float4* __restrict__ egoT,
    float4* __restrict__ out)
{
    int tid = blockIdx.x * 256 + threadIdx.x;
    int row = tid >> 5, q = tid & 31;
    if (row >= NTOT) return;
    float4 v = (q < 16) ? egoI[(size_t)row * 16 + q] : egoT[(size_t)row * 16 + (q - 16)];
    out[tid] = v;
}

// ============================================================================
extern "C" void kernel_launch(void* const* d_in, const int* in_sizes, int n_in,
                              void* d_out, int out_size, void* d_ws, size_t ws_size,
                              hipStream_t stream)
{
    const float* image_feats = (const float*)d_in[0];
    const float* text_feats  = (const float*)d_in[1];
    const float* image_pref  = (const float*)d_in[2];
    const float* text_pref   = (const float*)d_in[3];
    const float* W_img       = (const float*)d_in[4];
    const float* b_img       = (const float*)d_in[5];
    const float* W_txt       = (const float*)d_in[6];
    const float* b_txt       = (const float*)d_in[7];
    const float* adj_vals    = (const float*)d_in[8];
    const int*   adj_rows    = (const int*)d_in[9];
    const int*   adj_cols    = (const int*)d_in[10];

    float* out = (float*)d_out;
    char*  ws  = (char*)d_ws;

    // ---- workspace layout (sorted-CSR fast path) ----
    const size_t OFF_X1      = 0;                       // 19.2M floats = 76,800,000 B
    const size_t OFF_SPAIR   = 76800000;                // 6.4M int2   = 51,200,000 B
    const size_t OFF_RSTART  = 128000000;               // 150001 int  -> pad to 600,016 B
    const size_t OFF_CURSOR  = 128600016;               // 150000 int  = 600,000 B
    const size_t OFF_PART    = 129200016;               // 256 int
    const size_t NEED        = 129201040;

    if (ws_size >= NEED) {
        float* X1     = (float*)(ws + OFF_X1);
        int2*  spair  = (int2*) (ws + OFF_SPAIR);
        int*   rstart = (int*)  (ws + OFF_RSTART);
        int*   cursor = (int*)  (ws + OFF_CURSOR);
        int*   part   = (int*)  (ws + OFF_PART);

        // ---- build ego0 directly in d_out, interleaved [N][128] ----
        build_user<<<(N_USERS * 16 + 255) / 256, 256, 0, stream>>>(
            (const float4*)image_pref, (const float4*)text_pref, (float4*)out);
        float* items = out + (size_t)N_USERS * 128;
        gemm_bias<<<(N_ITEMS + 63) / 64, 256, 0, stream>>>(image_feats, W_img, b_img,
                                                           items, N_ITEMS, 4096, 128);
        gemm_bias<<<(N_ITEMS + 63) / 64, 256, 0, stream>>>(text_feats, W_txt, b_txt,
                                                           items + 64, N_ITEMS, 384, 128);
        l2norm_rows<<<(N_ITEMS + 3) / 4, 256, 0, stream>>>(items,      N_ITEMS, 128);
        l2norm_rows<<<(N_ITEMS + 3) / 4, 256, 0, stream>>>(items + 64, N_ITEMS, 128);

        // ---- counting sort of adjacency by row (once, reused by both layers) ----
        hipMemsetAsync(cursor, 0, (size_t)NTOT * sizeof(int), stream);   // cursor doubles as hist
        hist_k<<<NNZV / 256, 256, 0, stream>>>(adj_rows, cursor);
        const int NP = (NTOT + 1023) / 1024;  // 147
        scan_block<<<NP, 256, 0, stream>>>(cursor, rstart, part, NTOT);
        scan_partials<<<1, 256, 0, stream>>>(part, NP);
        add_offsets<<<(NTOT + 255) / 256, 256, 0, stream>>>(rstart, part, NTOT);
        set_tail<<<1, 64, 0, stream>>>(rstart);
        copy4<<<(NTOT / 4 + 255) / 256, 256, 0, stream>>>(
            (const float4*)rstart, (float4*)cursor, NTOT / 4);
        scatter_k<<<NNZV / 256, 256, 0, stream>>>(adj_vals, adj_rows, adj_cols, cursor, spair);

        // ---- 2 propagation layers, no atomics ----
        spmm_rows<<<NTOT / 4, 256, 0, stream>>>(spair, rstart, out, X1);  // layer 1: out -> X1
        spmm_rows<<<NTOT / 4, 256, 0, stream>>>(spair, rstart, X1, out);  // layer 2: X1 -> out
        return;
    }

    // ================= fallback: round-1 atomic path =================
    float* wsf = (float*)d_ws;
    float* Ai = wsf;
    float* At = wsf + SZ;
    float* Bi = out;
    float* Bt = out + SZ;

    const int n4_pref = N_USERS * DD / 4;
    const int n4_ego  = (int)(SZ / 4);

    copy4<<<n4_pref / 256, 256, 0, stream>>>((const float4*)image_pref, (float4*)Ai, n4_pref);
    copy4<<<n4_pref / 256, 256, 0, stream>>>((const float4*)text_pref,  (float4*)At, n4_pref);

    gemm_bias<<<(N_ITEMS + 63) / 64, 256, 0, stream>>>(image_feats, W_img, b_img,
                                                       Ai + (size_t)N_USERS * DD, N_ITEMS, 4096, DD);
    gemm_bias<<<(N_ITEMS + 63) / 64, 256, 0, stream>>>(text_feats,  W_txt, b_txt,
                                                       At + (size_t)N_USERS * DD, N_ITEMS, 384, DD);
    l2norm_rows<<<(N_ITEMS + 3) / 4, 256, 0, stream>>>(Ai + (size_t)N_USERS * DD, N_ITEMS, DD);
    l2norm_rows<<<(N_ITEMS + 3) / 4, 256, 0, stream>>>(At + (size_t)N_USERS * DD, N_ITEMS, DD);

    const int spmm_blocks = (int)(((long long)NNZV * 16 + 255) / 256);

    scale4<<<(n4_ego + 255) / 256, 256, 0, stream>>>((const float4*)Ai, (float4*)Bi, n4_ego);
    spmm_atomic<<<spmm_blocks, 256, 0, stream>>>(adj_vals, adj_rows, adj_cols, Ai, Bi, NNZV);
    scale4<<<(n4_ego + 255) / 256, 256, 0, stream>>>((const float4*)At, (float4*)Bt, n4_ego);
    spmm_atomic<<<spmm_blocks, 256, 0, stream>>>(adj_vals, adj_rows, adj_cols, At, Bt, NNZV);

    scale4<<<(n4_ego + 255) / 256, 256, 0, stream>>>((const float4*)Bi, (float4*)Ai, n4_ego);
    spmm_atomic<<<spmm_blocks, 256, 0, stream>>>(adj_vals, adj_rows, adj_cols, Bi, Ai, NNZV);
    scale4<<<(n4_ego + 255) / 256, 256, 0, stream>>>((const float4*)Bt, (float4*)At, n4_ego);
    spmm_atomic<<<spmm_blocks, 256, 0, stream>>>(adj_vals, adj_rows, adj_cols, Bt, At, NNZV);

    finalize_k<<<(NTOT * 32) / 256, 256, 0, stream>>>((const float4*)Ai, (const float4*)At,
                                                      (float4*)out);
}